// Round 12
// baseline (155.044 us; speedup 1.0000x reference)
//
#include <hip/hip_runtime.h>

// Problem constants
#define NB     16
#define LATD   512
#define FIN_C  128
#define FOUT_C 128
#define KK     3
#define HW     64
#define KSZ    147456      // FOUT*FIN*K*K
#define NROWS  147584      // KSZ + FOUT (bias rows)

// padded channel-last x: [b][66][66][128]
#define XPAD   66
#define XT_BE  ((size_t)XPAD * XPAD * FIN_C)  // 557568 elems per b

// workspace layout (bytes) — single-bf16 scheme (no lo arrays)
#define AFH_OFF  ((size_t)0)
#define AF_BYTES ((size_t)NB * KSZ * 2)          // 4,718,592
#define XTH_OFF  (AFH_OFF + AF_BYTES)
#define XT_BYTES ((size_t)NB * XT_BE * 2)        // 17,842,176
#define KST_OFF  (XTH_OFF + XT_BYTES)            // ks_tmp[n][16] fp32
#define KST_BYTES ((size_t)KSZ * NB * 4)         // 9,437,184
#define BIAS_OFF (KST_OFF + KST_BYTES)
#define LATFH_OFF (BIAS_OFF + (size_t)NB * FOUT_C * 4)
#define LATF_BYTES ((size_t)NB * LATD * 2)       // 16,384
#define WS_NEED  (LATFH_OFF + LATF_BYTES)

typedef __attribute__((ext_vector_type(8))) short bf16x8;
typedef __attribute__((ext_vector_type(4))) float f32x4;
typedef __attribute__((ext_vector_type(2))) float f32x2;

#define GLOAD16(gp, lp)                                                        \
  __builtin_amdgcn_global_load_lds(                                            \
      (const __attribute__((address_space(1))) void*)(gp),                     \
      (__attribute__((address_space(3))) void*)(lp), 16, 0, 0)

// Explicit drain of this wave's outstanding global_load_lds BEFORE the
// barrier (R3 post-mortem race fix): __syncthreads() alone lets the compiler
// sink the per-wave vmcnt wait past s_barrier.
#define VMCNT0_BARRIER()                                                       \
  do {                                                                         \
    asm volatile("s_waitcnt vmcnt(0)" ::: "memory");                           \
    __syncthreads();                                                           \
  } while (0)

__device__ __forceinline__ unsigned short f2bf(float f) {
  unsigned u = __builtin_bit_cast(unsigned, f);
  u += 0x7fffu + ((u >> 16) & 1u);       // RNE
  return (unsigned short)(u >> 16);
}

// 8 floats -> bf16x8 (RNE)
__device__ __forceinline__ bf16x8 cvt8(float4 a, float4 b) {
  bf16x8 h;
  h[0] = (short)f2bf(a.x); h[1] = (short)f2bf(a.y);
  h[2] = (short)f2bf(a.z); h[3] = (short)f2bf(a.w);
  h[4] = (short)f2bf(b.x); h[5] = (short)f2bf(b.y);
  h[6] = (short)f2bf(b.z); h[7] = (short)f2bf(b.w);
  return h;
}

// Af linear index d -> W row index n (A-fragment order for 16x16x32 MFMA)
__device__ __forceinline__ int dton(int d) {
  int e = d & 7, l = (d >> 3) & 63, mt = (d >> 9) & 7;
  int fib = (d >> 12) & 3, t = d >> 14;
  int fo = mt * 16 + (l & 15);
  int fi = fib * 32 + (l >> 4) * 8 + e;
  return fo * (FIN_C * KK * KK) + fi * (KK * KK) + t;
}

// ---------------------------------------------------------------------------
// Kernel 0: latprep — lat fp32 -> bf16 A-fragments in global (16 KB,
// L2-resident).  Granule g = it*64 + lane: lat[b=lane&15][it*32+(lane>>4)*8+e].
// ---------------------------------------------------------------------------
__global__ __launch_bounds__(256) void latprep(
    const float* __restrict__ lat, unsigned short* __restrict__ latFh) {
  const int t = threadIdx.x;
#pragma unroll
  for (int rr = 0; rr < 4; ++rr) {
    int g = t + rr * 256;              // 0..1023
    int it = g >> 6, lane = g & 63;
    int b = lane & 15;
    int k0 = it * 32 + (lane >> 4) * 8;
    float4 a = *(const float4*)(lat + b * LATD + k0);
    float4 bb = *(const float4*)(lat + b * LATD + k0 + 4);
    *(bf16x8*)(latFh + (size_t)g * 8) = cvt8(a, bb);
  }
}

// ---------------------------------------------------------------------------
// Kernel 1: hyper GEMM v4 — PERFECTLY LINEAR W reads.
// R11 post-mortem: v2 (VGPR-stream) and v3 (LDS-staged K-tiles) BOTH cap at
// ~3.0 TB/s; shared trait = strided sub-page DRAM bursts (v3: 256B segments
// @2KB stride, 8 page revisits).  v4 stages the block's ENTIRE [32 rows][512]
// fp32 panel (64 KB) in one shot with lds_dst = gg*16, src = base + gg*4 —
// byte-linear (1 KB contiguous per wave instruction, 64 KB per block).
// Single buffer + one vmcnt0-barrier; pipelining via 2 blocks/CU (66 KB LDS).
// 4 waves = 2 row-groups x 2 K-halves, 8 MFMAs each; 2 KB LDS reduction
// combines K-halves.  Known + budgeted: 16-way bank conflict on wtile reads
// (2KB row stride) ~8.4K cyc/CU-round < 13K cyc BW time — off critical path.
// Coverage: 4608 blocks x 32 rows = 147456 exact (+1 bias block).
// DECISIVE TEST: page theory -> ~55us; unchanged -> read-path ceiling, roofline.
// ---------------------------------------------------------------------------
__global__ __launch_bounds__(256, 2) void hyper_gemm_mfma4(
    const float* __restrict__ lat, const float* __restrict__ W,
    const float* __restrict__ bvec, const unsigned short* __restrict__ latFh,
    float* __restrict__ ks_tmp, float* __restrict__ bias_ws) {
  __shared__ float wtile[32 * 512];      // 64 KB, single buffer
  __shared__ f32x4 red[2][64];           // 2 KB K-half reduction
  const int bid = blockIdx.x, tid = threadIdx.x;

  if (bid == 4608) {                     // bias rows (straggler, hidden)
    if (tid >= FOUT_C) return;
    int n = KSZ + tid;
    const float4* w4 = (const float4*)(W + (size_t)n * LATD);
    f32x2 acc[NB] = {};
#pragma unroll 4
    for (int k4 = 0; k4 < LATD / 4; ++k4) {
      float4 wv = w4[k4];
      f32x2 w01 = {wv.x, wv.y}, w23 = {wv.z, wv.w};
#pragma unroll
      for (int b = 0; b < NB; ++b) {
        float4 lv = *(const float4*)(lat + b * LATD + k4 * 4);  // uniform
        f32x2 l01 = {lv.x, lv.y}, l23 = {lv.z, lv.w};
        acc[b] = __builtin_elementwise_fma(w01, l01, acc[b]);
        acc[b] = __builtin_elementwise_fma(w23, l23, acc[b]);
      }
    }
    float bv = bvec[n];
#pragma unroll
    for (int b = 0; b < NB; ++b)
      bias_ws[b * FOUT_C + tid] = acc[b].x + acc[b].y + bv;
    return;
  }

  const int l = tid & 63, w = tid >> 6;
  const int n0b = bid * 32;              // block's 32 consecutive W rows

  // ---- stage: 64 KB, byte-linear.  addr(gg) = W + n0b*512 + gg*4 exactly.
  const float* src = W + (size_t)n0b * LATD;
#pragma unroll
  for (int r = 0; r < 16; ++r) {
    int gg = r * 256 + tid;              // granule 0..4095 (16 B each)
    GLOAD16(src + (size_t)gg * 4, (char*)wtile + (size_t)gg * 16);
  }
  VMCNT0_BARRIER();                      // panel landed for ALL waves

  // ---- compute: wave = (row-group rg, K-half kh)
  const int rg = w >> 1, kh = w & 1;
  const int c = l & 15, kq = l >> 4;
  const bf16x8* lFh = (const bf16x8*)latFh + l;
  f32x4 acc = {};
#pragma unroll
  for (int it = 0; it < 8; ++it) {
    int ks = kh * 8 + it;                // overall K-step 0..15 (K=32 each)
    bf16x8 lah = lFh[ks * 64];           // lat A-frag (L2-resident)
    const float* base = wtile + (rg * 16 + c) * LATD + ks * 32 + kq * 8;
    float4 a = *(const float4*)(base);
    float4 b = *(const float4*)(base + 4);
    acc = __builtin_amdgcn_mfma_f32_16x16x32_bf16(lah, cvt8(a, b), acc, 0, 0, 0);
  }

  // ---- cross-wave K reduction (uniform barriers)
  if (kh == 1) red[rg][l] = acc;
  __syncthreads();
  if (kh == 0) {
    f32x4 o = red[rg][l];
    int nw = n0b + rg * 16;
    float bv = bvec[nw + c];
#pragma unroll
    for (int r = 0; r < 4; ++r)
      ks_tmp[(size_t)(nw + c) * NB + (kq * 4 + r)] = acc[r] + o[r] + bv;
  }
}

// ---------------------------------------------------------------------------
// Kernel 1b: reshuffle — ks_tmp[n][16b] fp32 -> Afh[b][d] bf16 (d-major,
// A-fragment order).  Gather 64B/thread (scatter borne by 9.4MB, not 302MB);
// stores fully coalesced per b.
// ---------------------------------------------------------------------------
__global__ __launch_bounds__(256) void reshuffle(
    const float* __restrict__ ks_tmp, unsigned short* __restrict__ Afh) {
  const int d = blockIdx.x * 256 + threadIdx.x;   // 576 blocks cover KSZ
  const int n = dton(d);
  const float4* p = (const float4*)(ks_tmp + (size_t)n * NB);
  float4 v0 = p[0], v1 = p[1], v2 = p[2], v3 = p[3];
  float v[16] = {v0.x, v0.y, v0.z, v0.w, v1.x, v1.y, v1.z, v1.w,
                 v2.x, v2.y, v2.z, v2.w, v3.x, v3.y, v3.z, v3.w};
#pragma unroll
  for (int b = 0; b < NB; ++b)
    Afh[(size_t)b * KSZ + d] = f2bf(v[b]);
}

// ---------------------------------------------------------------------------
// Kernel 2: prepass — x fp32 -> padded channel-last bf16 xT[b][y+1][x+1][fi].
// ---------------------------------------------------------------------------
__global__ __launch_bounds__(256) void prepass(
    const float* __restrict__ x, unsigned short* __restrict__ xTh) {
  __shared__ float tile[FIN_C * 65];     // pitch 65 to break bank conflicts
  const int y = blockIdx.x;              // 0..65 padded row
  const int b = blockIdx.y;
  const int tid = threadIdx.x;
  const bool interior = (y >= 1 && y <= HW);

  if (interior) {
    int yy = y - 1;
#pragma unroll
    for (int r = 0; r < 8; ++r) {
      int idx = tid + r * 256;           // 0..2047
      int fi = idx >> 4, q = idx & 15;
      float4 v = *(const float4*)(x + ((size_t)(b * FIN_C + fi) * (HW * HW)) +
                                  yy * HW + q * 4);
      float* dst = &tile[fi * 65 + q * 4];
      dst[0] = v.x; dst[1] = v.y; dst[2] = v.z; dst[3] = v.w;
    }
  }
  __syncthreads();

  for (int r = 0; r < 5; ++r) {
    int gg = tid + r * 256;              // granule: (x 0..65) x (fi8 0..15)
    if (gg >= XPAD * 16) break;
    int xc = gg >> 4, f8 = gg & 15;
    bf16x8 hv = {};
    if (interior && xc >= 1 && xc <= HW) {
#pragma unroll
      for (int e2 = 0; e2 < 8; ++e2) {
        float f = tile[(f8 * 8 + e2) * 65 + (xc - 1)];
        hv[e2] = (short)f2bf(f);
      }
    }
    size_t off = ((size_t)b * XPAD * XPAD + (size_t)y * XPAD + xc) * FIN_C + f8 * 8;
    *(bf16x8*)(xTh + off) = hv;
  }
}

// ---------------------------------------------------------------------------
// Kernel 3: MFMA conv, single bf16 product (error budget ~0.5 absmax vs
// 1.93 threshold), double-buffered 2-phase schedule:
//   STAGE(s+1, other buf) -> ds_read+MFMA(s) -> vmcnt(0) -> barrier.
// LDS 32 KB = 2 x (Ah | Bh); 3 blocks/CU.   ** Proven — unchanged. **
// ---------------------------------------------------------------------------
__global__ __launch_bounds__(256, 3) void dyn_conv_mfma(
    const unsigned short* __restrict__ Afh, const unsigned short* __restrict__ xTh,
    const float* __restrict__ bias_ws, float* __restrict__ out) {
  __shared__ bf16x8 lds[2048];           // 32 KB: granules, buf1 at +1024
  char* ldsb = (char*)lds;
  const int pt = blockIdx.x;             // px tile (128 px = 2 image rows)
  const int b = blockIdx.y;
  const int tid = threadIdx.x;
  const int l = tid & 63;
  const int wid = tid >> 6;
  const int wr = wid >> 1, wc = wid & 1; // wave tile: 64 fo x 64 px

  f32x4 acc[4][4] = {};

  auto stage = [&](int s, int bufg) {    // bufg = granule base (0 or 1024)
    const int t = s >> 2, fib = s & 3;
    const int dy = t / 3 - 1, dx = t % 3 - 1;
    const size_t abase = (size_t)b * KSZ + (size_t)s * 4096;  // s == t*4+fib
    char* base0 = ldsb + (size_t)bufg * 16;
#pragma unroll
    for (int r = 0; r < 2; ++r) {
      int g = tid + r * 256;
      GLOAD16(Afh + abase + (size_t)g * 8, base0 + g * 16);
    }
#pragma unroll
    for (int r = 0; r < 2; ++r) {
      int g = tid + r * 256;
      int px = g >> 2;
      int fq = (g & 3) ^ (px & 3);       // inverse swizzle on source
      int yy = 2 * pt + (px >> 6) + dy + 1;
      int xx = (px & 63) + dx + 1;
      size_t boff = ((size_t)b * XPAD * XPAD + (size_t)yy * XPAD + xx) * FIN_C +
                    fib * 32 + fq * 8;
      GLOAD16(xTh + boff, base0 + 8192 + g * 16);
    }
  };

  stage(0, 0);
  VMCNT0_BARRIER();                      // buf0 fully landed for ALL waves

  for (int s = 0; s < 36; ++s) {
    const int cg = (s & 1) * 1024;       // current buffer granule base
    if (s < 35) stage(s + 1, 1024 - cg); // prefetch next into other buffer

    bf16x8 ah[4];
#pragma unroll
    for (int m = 0; m < 4; ++m)
      ah[m] = lds[cg + (wr * 4 + m) * 64 + l];
    const int kq = l >> 4;
#pragma unroll
    for (int nn = 0; nn < 4; ++nn) {
      int px = wc * 64 + nn * 16 + (l & 15);
      int slot = px * 4 + (kq ^ (px & 3));
      bf16x8 bh = lds[cg + 512 + slot];
#pragma unroll
      for (int m = 0; m < 4; ++m)
        acc[m][nn] = __builtin_amdgcn_mfma_f32_16x16x32_bf16(ah[m], bh, acc[m][nn], 0, 0, 0);
    }
    VMCNT0_BARRIER();                    // drain next-tile DMA, then barrier
  }

  // ---- epilogue: D col = lane&15 (px), row = (lane>>4)*4 + reg (fo)
  float bvv[4][4];
#pragma unroll
  for (int m = 0; m < 4; ++m)
#pragma unroll
    for (int r = 0; r < 4; ++r)
      bvv[m][r] = bias_ws[b * FOUT_C + wr * 64 + m * 16 + (l >> 4) * 4 + r];

#pragma unroll
  for (int m = 0; m < 4; ++m) {
#pragma unroll
    for (int nn = 0; nn < 4; ++nn) {
#pragma unroll
      for (int r = 0; r < 4; ++r) {
        int fo = wr * 64 + m * 16 + (l >> 4) * 4 + r;
        int p = pt * 128 + wc * 64 + nn * 16 + (l & 15);
        out[((size_t)b * FOUT_C + fo) * (HW * HW) + p] = acc[m][nn][r] + bvv[m][r];
      }
    }
  }
}

// ===========================================================================
// Fallback (proven fp32 path) in case ws_size < WS_NEED
// ===========================================================================
__global__ __launch_bounds__(256) void hyper_gemm_fb(
    const float* __restrict__ lat, const float* __restrict__ W,
    const float* __restrict__ bvec, float* __restrict__ kt,
    float* __restrict__ bias_ws) {
  int d = blockIdx.x * 256 + threadIdx.x;
  if (d >= NROWS) return;
  long n; int fo; bool isBias = (d >= KSZ);
  if (!isBias) {
    fo = d & 127; int rest = d >> 7; int tap = rest % 9; int fi = rest / 9;
    n = (long)fo * (FIN_C * KK * KK) + fi * (KK * KK) + tap;
  } else { fo = d - KSZ; n = KSZ + fo; }
  const float* wrow = W + n * LATD;
  float bv = bvec[n];
  float acc[NB];
#pragma unroll
  for (int b = 0; b < NB; ++b) acc[b] = bv;
#pragma unroll 2
  for (int k = 0; k < LATD; k += 4) {
    float4 wv = *reinterpret_cast<const float4*>(wrow + k);
#pragma unroll
    for (int b = 0; b < NB; ++b) {
      acc[b] += wv.x * lat[b * LATD + k] + wv.y * lat[b * LATD + k + 1] +
                wv.z * lat[b * LATD + k + 2] + wv.w * lat[b * LATD + k + 3];
    }
  }
  if (!isBias) {
#pragma unroll
    for (int b = 0; b < NB; ++b) kt[(long)b * KSZ + d] = acc[b];
  } else {
#pragma unroll
    for (int b = 0; b < NB; ++b) bias_ws[b * FOUT_C + fo] = acc[b];
  }
}

__global__ __launch_bounds__(64) void dyn_conv_fb(
    const float* __restrict__ x, const float* __restrict__ kt,
    const float* __restrict__ bias_ws, float* __restrict__ out) {
  const int h = blockIdx.x, b = blockIdx.y, fo0 = blockIdx.z * 32;
  const int w = threadIdx.x;
  const float* xb = x + (long)b * FIN_C * (HW * HW);
  const float* ktb = kt + (long)b * KSZ;
  const float* bb = bias_ws + b * FOUT_C + fo0;
  float acc[32];
#pragma unroll
  for (int j = 0; j < 32; ++j) acc[j] = bb[j];
  for (int fi = 0; fi < FIN_C; ++fi) {
    float xv[9];
    const float* xr = xb + fi * (HW * HW);
#pragma unroll
    for (int ky = 0; ky < 3; ++ky) {
      int hy = h + ky - 1;
      bool vr = (hy >= 0) && (hy < HW);
      const float* row = xr + hy * HW;
      xv[ky * 3 + 0] = (vr && w > 0) ? row[w - 1] : 0.f;
      xv[ky * 3 + 1] = vr ? row[w] : 0.f;
      xv[ky * 3 + 2] = (vr && w < 63) ? row[w + 1] : 0.f;
    }
    const float* wt = ktb + fi * (KK * KK * FOUT_C) + fo0;
#pragma unroll
    for (int t = 0; t < 9; ++t)
#pragma unroll
      for (int j = 0; j < 32; ++j) acc[j] += xv[t] * wt[t * FOUT_C + j];
  }
  float* ob = out + (((long)b * FOUT_C + fo0) * HW + h) * HW + w;
#pragma unroll
  for (int j = 0; j < 32; ++j) ob[(long)j * (HW * HW)] = acc[j];
}

// ---------------------------------------------------------------------------
extern "C" void kernel_launch(void* const* d_in, const int* in_sizes, int n_in,
                              void* d_out, int out_size, void* d_ws, size_t ws_size,
                              hipStream_t stream) {
  const float* x   = (const float*)d_in[0];
  const float* lat = (const float*)d_in[1];
  const float* W   = (const float*)d_in[2];
  const float* bv  = (const float*)d_in[3];
  float* out = (float*)d_out;
  char* ws = (char*)d_ws;

  if (ws_size >= WS_NEED) {
    unsigned short* Afh = (unsigned short*)(ws + AFH_OFF);
    unsigned short* xTh = (unsigned short*)(ws + XTH_OFF);
    float* ks_tmp = (float*)(ws + KST_OFF);
    float* bias_ws = (float*)(ws + BIAS_OFF);
    unsigned short* latFh = (unsigned short*)(ws + LATFH_OFF);

    latprep<<<dim3(1), dim3(256), 0, stream>>>(lat, latFh);
    hyper_gemm_mfma4<<<dim3(4609), dim3(256), 0, stream>>>(
        lat, W, bv, latFh, ks_tmp, bias_ws);
    reshuffle<<<dim3(576), dim3(256), 0, stream>>>(ks_tmp, Afh);
    prepass<<<dim3(XPAD, NB), dim3(256), 0, stream>>>(x, xTh);
    dyn_conv_mfma<<<dim3(32, NB), dim3(256), 0, stream>>>(Afh, xTh, bias_ws, out);
  } else {
    float* kt = (float*)d_ws;
    float* bias_ws = kt + (size_t)NB * KSZ;
    hyper_gemm_fb<<<dim3((NROWS + 255) / 256), dim3(256), 0, stream>>>(lat, W, bv, kt, bias_ws);
    dyn_conv_fb<<<dim3(HW, NB, 4), dim3(64), 0, stream>>>(x, kt, bias_ws, out);
  }
}

// Round 14
// 123.042 us; speedup vs baseline: 1.2601x; 1.2601x over previous
//
#include <hip/hip_runtime.h>

// Problem constants
#define NB     16
#define LATD   512
#define FIN_C  128
#define FOUT_C 128
#define KK     3
#define HW     64
#define KSZ    147456      // FOUT*FIN*K*K
#define NROWS  147584      // KSZ + FOUT (bias rows)

// padded channel-last x: [b][66][66][128]
#define XPAD   66
#define XT_BE  ((size_t)XPAD * XPAD * FIN_C)  // 557568 elems per b

// workspace layout (bytes)
#define AFH_OFF  ((size_t)0)
#define AF_BYTES ((size_t)NB * KSZ * 2)          // 4,718,592
#define XTH_OFF  (AFH_OFF + AF_BYTES)
#define XT_BYTES ((size_t)NB * XT_BE * 2)        // 17,842,176
#define KST_OFF  (XTH_OFF + XT_BYTES)            // ks_tmp[n][16] fp32
#define KST_BYTES ((size_t)KSZ * NB * 4)         // 9,437,184
#define BIAS_OFF (KST_OFF + KST_BYTES)
#define WS_NEED  (BIAS_OFF + (size_t)NB * FOUT_C * 4)

// fused-kernel block ranges
#define NPRE   1056                      // 16 b x 66 y prepass blocks (first)
#define BIASB  NPRE                      // bias block
#define GEMM0  (NPRE + 1)                // gemm blocks start
#define NGEMM  1152                      // x 128 rows = 147456 exact
#define NFUSED (GEMM0 + NGEMM)           // 2209

typedef __attribute__((ext_vector_type(8))) short bf16x8;
typedef __attribute__((ext_vector_type(4))) float f32x4;
typedef __attribute__((ext_vector_type(2))) float f32x2;

#define GLOAD16(gp, lp)                                                        \
  __builtin_amdgcn_global_load_lds(                                            \
      (const __attribute__((address_space(1))) void*)(gp),                     \
      (__attribute__((address_space(3))) void*)(lp), 16, 0, 0)

// Explicit drain of this wave's outstanding global_load_lds BEFORE the
// barrier (R3 post-mortem race fix): __syncthreads() alone lets the compiler
// sink the per-wave vmcnt wait past s_barrier.
#define VMCNT0_BARRIER()                                                       \
  do {                                                                         \
    asm volatile("s_waitcnt vmcnt(0)" ::: "memory");                           \
    __syncthreads();                                                           \
  } while (0)

__device__ __forceinline__ unsigned short f2bf(float f) {
  unsigned u = __builtin_bit_cast(unsigned, f);
  u += 0x7fffu + ((u >> 16) & 1u);       // RNE
  return (unsigned short)(u >> 16);
}

// 8 floats -> bf16x8 (RNE)
__device__ __forceinline__ bf16x8 cvt8(float4 a, float4 b) {
  bf16x8 h;
  h[0] = (short)f2bf(a.x); h[1] = (short)f2bf(a.y);
  h[2] = (short)f2bf(a.z); h[3] = (short)f2bf(a.w);
  h[4] = (short)f2bf(b.x); h[5] = (short)f2bf(b.y);
  h[6] = (short)f2bf(b.z); h[7] = (short)f2bf(b.w);
  return h;
}

// Af linear index d -> W row index n (A-fragment order for 16x16x32 MFMA)
__device__ __forceinline__ int dton(int d) {
  int e = d & 7, l = (d >> 3) & 63, mt = (d >> 9) & 7;
  int fib = (d >> 12) & 3, t = d >> 14;
  int fo = mt * 16 + (l & 15);
  int fi = fib * 32 + (l >> 4) * 8 + e;
  return fo * (FIN_C * KK * KK) + fi * (KK * KK) + t;
}

// ---------------------------------------------------------------------------
// FUSED kernel: [0,1056) prepass | 1056 bias | [1057,2209) v2-GEMM.
// R12 post-mortem: v2(VGPR-stream)=100us, v3(DMA tiles)=105, v4(linear
// panels)=113 all cap at ~3.0 TB/s -> structural read-stream ceiling (copy
// m13 6.29 TB/s aggregate = ~3.15/dir; 7 TB/s fill is write-only).  The GEMM
// rate can't improve, so hide the REST of the chain in it: prepass traffic
// (34 MB) rides inside the BW-bound GEMM (VALU ~90% idle), and latprep is
// eliminated (each wave builds its lat A-frag from L2-hot lat + cvt8).
// No cross-block deps: prepass writes xTh (read by later conv kernel only).
// Prepass uses two fi-halves so LDS = 16.6 KB (doesn't cap gemm occupancy).
// ---------------------------------------------------------------------------
__global__ __launch_bounds__(256, 4) void fused_gemm_prepass(
    const float* __restrict__ x, const float* __restrict__ lat,
    const float* __restrict__ W, const float* __restrict__ bvec,
    float* __restrict__ ks_tmp, float* __restrict__ bias_ws,
    unsigned short* __restrict__ xTh) {
  __shared__ float tile[64 * 65];        // 16.64 KB (prepass branch only)
  const int bid = blockIdx.x, tid = threadIdx.x;

  if (bid < NPRE) {                      // ---------- prepass ----------
    const int y = bid % XPAD, b = bid / XPAD;
    const bool interior = (y >= 1 && y <= HW);
#pragma unroll
    for (int hh = 0; hh < 2; ++hh) {     // fi halves 0..63 / 64..127
      if (interior) {
        int yy = y - 1;
#pragma unroll
        for (int r = 0; r < 4; ++r) {
          int idx = tid + r * 256;       // 0..1023
          int fr = idx >> 4, q = idx & 15;
          float4 v = *(const float4*)(
              x + ((size_t)(b * FIN_C + hh * 64 + fr) * (HW * HW)) + yy * HW +
              q * 4);
          float* dst = &tile[fr * 65 + q * 4];
          dst[0] = v.x; dst[1] = v.y; dst[2] = v.z; dst[3] = v.w;
        }
      }
      __syncthreads();
      for (int r = 0; r < 3; ++r) {
        int gg = tid + r * 256;          // 0..527 = (x 0..65) x (f8h 0..7)
        if (gg < XPAD * 8) {
          int xc = gg >> 3, f8h = gg & 7;
          bf16x8 hv = {};
          if (interior && xc >= 1 && xc <= HW) {
#pragma unroll
            for (int e2 = 0; e2 < 8; ++e2)
              hv[e2] = (short)f2bf(tile[(f8h * 8 + e2) * 65 + (xc - 1)]);
          }
          size_t off = ((size_t)b * XPAD * XPAD + (size_t)y * XPAD + xc) * FIN_C +
                       (hh * 8 + f8h) * 8;
          *(bf16x8*)(xTh + off) = hv;
        }
      }
      __syncthreads();                   // tile reuse fence (uniform)
    }
    return;
  }

  if (bid == BIASB) {                    // ---------- bias rows ----------
    if (tid >= FOUT_C) return;
    int n = KSZ + tid;
    const float4* w4 = (const float4*)(W + (size_t)n * LATD);
    f32x2 acc[NB] = {};
#pragma unroll 4
    for (int k4 = 0; k4 < LATD / 4; ++k4) {
      float4 wv = w4[k4];
      f32x2 w01 = {wv.x, wv.y}, w23 = {wv.z, wv.w};
#pragma unroll
      for (int b = 0; b < NB; ++b) {
        float4 lv = *(const float4*)(lat + b * LATD + k4 * 4);  // uniform
        f32x2 l01 = {lv.x, lv.y}, l23 = {lv.z, lv.w};
        acc[b] = __builtin_elementwise_fma(w01, l01, acc[b]);
        acc[b] = __builtin_elementwise_fma(w23, l23, acc[b]);
      }
    }
    float bv = bvec[n];
#pragma unroll
    for (int b = 0; b < NB; ++b)
      bias_ws[b * FOUT_C + tid] = acc[b].x + acc[b].y + bv;
    return;
  }

  // ---------- v2 GEMM (proven fastest: ~100us, ~3.0 TB/s wall) ----------
  const int g = bid - GEMM0;
  const int l = tid & 63, wid = tid >> 6;
  const int n0 = g * 128 + wid * 32;     // 32 consecutive W rows per wave
  const int c = l & 15, kq = l >> 4;     // coverage: 1152*128 = 147456 exact
  const float* wp0 = W + (size_t)(n0 + c) * LATD + kq * 8;
  const float* wp1 = W + (size_t)(n0 + 16 + c) * LATD + kq * 8;
  const float* latrow = lat + c * LATD + kq * 8;  // A-frag source (L2-hot)

  f32x4 acc0 = {}, acc1 = {};
#pragma unroll
  for (int it = 0; it < 16; ++it) {      // K = 16 x 32; offsets fold to imm
    const float* lp = latrow + it * 32;  // lat[b=c][it*32+kq*8 ..], direct
    bf16x8 lah = cvt8(*(const float4*)lp, *(const float4*)(lp + 4));
    float4 a0 = *(const float4*)(wp0 + it * 32);
    float4 b0 = *(const float4*)(wp0 + it * 32 + 4);
    float4 a1 = *(const float4*)(wp1 + it * 32);
    float4 b1 = *(const float4*)(wp1 + it * 32 + 4);
    bf16x8 h0 = cvt8(a0, b0), h1 = cvt8(a1, b1);
    acc0 = __builtin_amdgcn_mfma_f32_16x16x32_bf16(lah, h0, acc0, 0, 0, 0);
    acc1 = __builtin_amdgcn_mfma_f32_16x16x32_bf16(lah, h1, acc1, 0, 0, 0);
  }

  // epilogue: C row = b = kq*4+r, col = c.  ks_tmp[n][b] = acc + bvec[n].
  const float bv0 = bvec[n0 + c];
  const float bv1 = bvec[n0 + 16 + c];
#pragma unroll
  for (int r = 0; r < 4; ++r) {
    int b = kq * 4 + r;
    ks_tmp[(size_t)(n0 + c) * NB + b] = acc0[r] + bv0;
    ks_tmp[(size_t)(n0 + 16 + c) * NB + b] = acc1[r] + bv1;
  }
}

// ---------------------------------------------------------------------------
// Kernel 1b: reshuffle — ks_tmp[n][16b] fp32 -> Afh[b][d] bf16 (d-major,
// A-fragment order).  Gather 64B/thread; stores fully coalesced per b.
// ---------------------------------------------------------------------------
__global__ __launch_bounds__(256) void reshuffle(
    const float* __restrict__ ks_tmp, unsigned short* __restrict__ Afh) {
  const int d = blockIdx.x * 256 + threadIdx.x;   // 576 blocks cover KSZ
  const int n = dton(d);
  const float4* p = (const float4*)(ks_tmp + (size_t)n * NB);
  float4 v0 = p[0], v1 = p[1], v2 = p[2], v3 = p[3];
  float v[16] = {v0.x, v0.y, v0.z, v0.w, v1.x, v1.y, v1.z, v1.w,
                 v2.x, v2.y, v2.z, v2.w, v3.x, v3.y, v3.z, v3.w};
#pragma unroll
  for (int b = 0; b < NB; ++b)
    Afh[(size_t)b * KSZ + d] = f2bf(v[b]);
}

// ---------------------------------------------------------------------------
// Kernel 3: MFMA conv, single bf16 product (absmax 0.5 vs 1.93 threshold),
// double-buffered 2-phase schedule:
//   STAGE(s+1, other buf) -> ds_read+MFMA(s) -> vmcnt(0) -> barrier.
// LDS 32 KB = 2 x (Ah | Bh); 3 blocks/CU.   ** Proven — unchanged. **
// ---------------------------------------------------------------------------
__global__ __launch_bounds__(256, 3) void dyn_conv_mfma(
    const unsigned short* __restrict__ Afh, const unsigned short* __restrict__ xTh,
    const float* __restrict__ bias_ws, float* __restrict__ out) {
  __shared__ bf16x8 lds[2048];           // 32 KB: granules, buf1 at +1024
  char* ldsb = (char*)lds;
  const int pt = blockIdx.x;             // px tile (128 px = 2 image rows)
  const int b = blockIdx.y;
  const int tid = threadIdx.x;
  const int l = tid & 63;
  const int wid = tid >> 6;
  const int wr = wid >> 1, wc = wid & 1; // wave tile: 64 fo x 64 px

  f32x4 acc[4][4] = {};

  auto stage = [&](int s, int bufg) {    // bufg = granule base (0 or 1024)
    const int t = s >> 2, fib = s & 3;
    const int dy = t / 3 - 1, dx = t % 3 - 1;
    const size_t abase = (size_t)b * KSZ + (size_t)s * 4096;  // s == t*4+fib
    char* base0 = ldsb + (size_t)bufg * 16;
#pragma unroll
    for (int r = 0; r < 2; ++r) {
      int g = tid + r * 256;
      GLOAD16(Afh + abase + (size_t)g * 8, base0 + g * 16);
    }
#pragma unroll
    for (int r = 0; r < 2; ++r) {
      int g = tid + r * 256;
      int px = g >> 2;
      int fq = (g & 3) ^ (px & 3);       // inverse swizzle on source
      int yy = 2 * pt + (px >> 6) + dy + 1;
      int xx = (px & 63) + dx + 1;
      size_t boff = ((size_t)b * XPAD * XPAD + (size_t)yy * XPAD + xx) * FIN_C +
                    fib * 32 + fq * 8;
      GLOAD16(xTh + boff, base0 + 8192 + g * 16);
    }
  };

  stage(0, 0);
  VMCNT0_BARRIER();                      // buf0 fully landed for ALL waves

  for (int s = 0; s < 36; ++s) {
    const int cg = (s & 1) * 1024;       // current buffer granule base
    if (s < 35) stage(s + 1, 1024 - cg); // prefetch next into other buffer

    bf16x8 ah[4];
#pragma unroll
    for (int m = 0; m < 4; ++m)
      ah[m] = lds[cg + (wr * 4 + m) * 64 + l];
    const int kq = l >> 4;
#pragma unroll
    for (int nn = 0; nn < 4; ++nn) {
      int px = wc * 64 + nn * 16 + (l & 15);
      int slot = px * 4 + (kq ^ (px & 3));
      bf16x8 bh = lds[cg + 512 + slot];
#pragma unroll
      for (int m = 0; m < 4; ++m)
        acc[m][nn] = __builtin_amdgcn_mfma_f32_16x16x32_bf16(ah[m], bh, acc[m][nn], 0, 0, 0);
    }
    VMCNT0_BARRIER();                    // drain next-tile DMA, then barrier
  }

  // ---- epilogue: D col = lane&15 (px), row = (lane>>4)*4 + reg (fo)
  float bvv[4][4];
#pragma unroll
  for (int m = 0; m < 4; ++m)
#pragma unroll
    for (int r = 0; r < 4; ++r)
      bvv[m][r] = bias_ws[b * FOUT_C + wr * 64 + m * 16 + (l >> 4) * 4 + r];

#pragma unroll
  for (int m = 0; m < 4; ++m) {
#pragma unroll
    for (int nn = 0; nn < 4; ++nn) {
#pragma unroll
      for (int r = 0; r < 4; ++r) {
        int fo = wr * 64 + m * 16 + (l >> 4) * 4 + r;
        int p = pt * 128 + wc * 64 + nn * 16 + (l & 15);
        out[((size_t)b * FOUT_C + fo) * (HW * HW) + p] = acc[m][nn][r] + bvv[m][r];
      }
    }
  }
}

// ===========================================================================
// Fallback (proven fp32 path) in case ws_size < WS_NEED
// ===========================================================================
__global__ __launch_bounds__(256) void hyper_gemm_fb(
    const float* __restrict__ lat, const float* __restrict__ W,
    const float* __restrict__ bvec, float* __restrict__ kt,
    float* __restrict__ bias_ws) {
  int d = blockIdx.x * 256 + threadIdx.x;
  if (d >= NROWS) return;
  long n; int fo; bool isBias = (d >= KSZ);
  if (!isBias) {
    fo = d & 127; int rest = d >> 7; int tap = rest % 9; int fi = rest / 9;
    n = (long)fo * (FIN_C * KK * KK) + fi * (KK * KK) + tap;
  } else { fo = d - KSZ; n = KSZ + fo; }
  const float* wrow = W + n * LATD;
  float bv = bvec[n];
  float acc[NB];
#pragma unroll
  for (int b = 0; b < NB; ++b) acc[b] = bv;
#pragma unroll 2
  for (int k = 0; k < LATD; k += 4) {
    float4 wv = *reinterpret_cast<const float4*>(wrow + k);
#pragma unroll
    for (int b = 0; b < NB; ++b) {
      acc[b] += wv.x * lat[b * LATD + k] + wv.y * lat[b * LATD + k + 1] +
                wv.z * lat[b * LATD + k + 2] + wv.w * lat[b * LATD + k + 3];
    }
  }
  if (!isBias) {
#pragma unroll
    for (int b = 0; b < NB; ++b) kt[(long)b * KSZ + d] = acc[b];
  } else {
#pragma unroll
    for (int b = 0; b < NB; ++b) bias_ws[b * FOUT_C + fo] = acc[b];
  }
}

__global__ __launch_bounds__(64) void dyn_conv_fb(
    const float* __restrict__ x, const float* __restrict__ kt,
    const float* __restrict__ bias_ws, float* __restrict__ out) {
  const int h = blockIdx.x, b = blockIdx.y, fo0 = blockIdx.z * 32;
  const int w = threadIdx.x;
  const float* xb = x + (long)b * FIN_C * (HW * HW);
  const float* ktb = kt + (long)b * KSZ;
  const float* bb = bias_ws + b * FOUT_C + fo0;
  float acc[32];
#pragma unroll
  for (int j = 0; j < 32; ++j) acc[j] = bb[j];
  for (int fi = 0; fi < FIN_C; ++fi) {
    float xv[9];
    const float* xr = xb + fi * (HW * HW);
#pragma unroll
    for (int ky = 0; ky < 3; ++ky) {
      int hy = h + ky - 1;
      bool vr = (hy >= 0) && (hy < HW);
      const float* row = xr + hy * HW;
      xv[ky * 3 + 0] = (vr && w > 0) ? row[w - 1] : 0.f;
      xv[ky * 3 + 1] = vr ? row[w] : 0.f;
      xv[ky * 3 + 2] = (vr && w < 63) ? row[w + 1] : 0.f;
    }
    const float* wt = ktb + fi * (KK * KK * FOUT_C) + fo0;
#pragma unroll
    for (int t = 0; t < 9; ++t)
#pragma unroll
      for (int j = 0; j < 32; ++j) acc[j] += xv[t] * wt[t * FOUT_C + j];
  }
  float* ob = out + (((long)b * FOUT_C + fo0) * HW + h) * HW + w;
#pragma unroll
  for (int j = 0; j < 32; ++j) ob[(long)j * (HW * HW)] = acc[j];
}

// ---------------------------------------------------------------------------
extern "C" void kernel_launch(void* const* d_in, const int* in_sizes, int n_in,
                              void* d_out, int out_size, void* d_ws, size_t ws_size,
                              hipStream_t stream) {
  const float* x   = (const float*)d_in[0];
  const float* lat = (const float*)d_in[1];
  const float* W   = (const float*)d_in[2];
  const float* bv  = (const float*)d_in[3];
  float* out = (float*)d_out;
  char* ws = (char*)d_ws;

  if (ws_size >= WS_NEED) {
    unsigned short* Afh = (unsigned short*)(ws + AFH_OFF);
    unsigned short* xTh = (unsigned short*)(ws + XTH_OFF);
    float* ks_tmp = (float*)(ws + KST_OFF);
    float* bias_ws = (float*)(ws + BIAS_OFF);

    fused_gemm_prepass<<<dim3(NFUSED), dim3(256), 0, stream>>>(
        x, lat, W, bv, ks_tmp, bias_ws, xTh);
    reshuffle<<<dim3(576), dim3(256), 0, stream>>>(ks_tmp, Afh);
    dyn_conv_mfma<<<dim3(32, NB), dim3(256), 0, stream>>>(Afh, xTh, bias_ws, out);
  } else {
    float* kt = (float*)d_ws;
    float* bias_ws = kt + (size_t)NB * KSZ;
    hyper_gemm_fb<<<dim3((NROWS + 255) / 256), dim3(256), 0, stream>>>(lat, W, bv, kt, bias_ws);
    dyn_conv_fb<<<dim3(HW, NB, 4), dim3(64), 0, stream>>>(x, kt, bias_ws, out);
  }
}